// Round 1
// baseline (425.737 us; speedup 1.0000x reference)
//
#include <hip/hip_runtime.h>
#include <math.h>

// Problem constants (fixed by setup_inputs): bs=16, ch=64, C=81, H=W=256
#define BS 16
#define CH 64
#define NC 81
#define HW 65536          // 256*256
#define FG 1              // FG_STCH
#define NJ (CH - FG)      // 63 items per batch
#define NITEMS (BS * NJ)  // 1008

// Kernel 1: max over H*W for each (b, c). One block per channel.
// 256 threads, each reduces 256 floats via 64 float4 loads.
__global__ __launch_bounds__(256) void max_prob_kernel(
    const float* __restrict__ pmp, float* __restrict__ max_prob) {
    const int bc = blockIdx.x;  // 0..1023
    const float4* p = (const float4*)(pmp + (size_t)bc * HW);
    const int t = threadIdx.x;
    float m = -INFINITY;
#pragma unroll
    for (int i = 0; i < 64; ++i) {
        float4 v = p[t + i * 256];
        m = fmaxf(m, fmaxf(fmaxf(v.x, v.y), fmaxf(v.z, v.w)));
    }
    // wave (64-lane) butterfly reduce
#pragma unroll
    for (int off = 32; off > 0; off >>= 1)
        m = fmaxf(m, __shfl_xor(m, off, 64));
    __shared__ float smax[4];
    if ((t & 63) == 0) smax[t >> 6] = m;
    __syncthreads();
    if (t == 0) {
        m = fmaxf(fmaxf(smax[0], smax[1]), fmaxf(smax[2], smax[3]));
        max_prob[bc] = m;
    }
}

// Kernel 2: all the gather / log-softmax / loss math + final reduction.
// Single block of 1024 threads; thread idx handles item idx (< 1008).
__global__ __launch_bounds__(1024) void loss_kernel(
    const float* __restrict__ cls_logits,   // (BS, CH, NC)
    const float* __restrict__ iou_scores,   // (BS, CH, 1)
    const int*   __restrict__ target_ids,   // (BS, CH)
    const int*   __restrict__ map_indices,  // (BS, 2, CH)
    const float* __restrict__ map_ious,     // (BS, CH)
    const float* __restrict__ rand_vals,    // (BS, CH)
    const float* __restrict__ max_prob,     // (BS, CH) in ws
    float* __restrict__ out)                // [iou_loss, cls_loss]
{
    const int idx = threadIdx.x;
    float sw = 0.f, si = 0.f, sc = 0.f;
    if (idx < NITEMS) {
        const int b = idx / NJ;
        const int j = idx - b * NJ + FG;          // FG..CH-1
        const int pj = map_indices[b * 2 * CH + j];
        const int gj = map_indices[b * 2 * CH + CH + j];
        const int tid_v = target_ids[b * CH + gj];
        int cls = tid_v - FG + 1;                 // = tid_v
        cls = cls > 0 ? cls : 0;
        const float iou = map_ious[b * CH + j];
        const float mp  = max_prob[b * CH + pj];
        const float rnd = rand_vals[b * CH + j];
        const bool remove = (mp < 0.1f) && (rnd < 0.9f);
        // w[] is all ones: wght = remove ? 0 : (iou < 0.2 ? 1 : 2)
        const float wght = remove ? 0.f : (iou < 0.2f ? 1.f : 2.f);
        // smooth L1 (theta = 0.1)
        const float preds_iou = iou_scores[b * CH + pj];
        const float y = fabsf(preds_iou - iou);
        const float il = (y < 0.1f) ? 5.f * y * y : (y - 0.05f);
        // log_softmax over NC logits at row (b, pj)
        const float* lg = cls_logits + ((size_t)(b * CH + pj)) * NC;
        float mx = -INFINITY;
        for (int c = 0; c < NC; ++c) mx = fmaxf(mx, lg[c]);
        float s = 0.f;
        for (int c = 0; c < NC; ++c) s += __expf(lg[c] - mx);
        const float logp = lg[cls] - mx - __logf(s);
        const float ce = -logp;                   // w[cls] == 1
        sw = wght;
        si = il * wght;
        sc = ce * wght;
    }
    // block reduce: 16 waves of 64
#pragma unroll
    for (int off = 32; off > 0; off >>= 1) {
        sw += __shfl_xor(sw, off, 64);
        si += __shfl_xor(si, off, 64);
        sc += __shfl_xor(sc, off, 64);
    }
    __shared__ float s0[16], s1[16], s2[16];
    const int wv = idx >> 6;
    if ((idx & 63) == 0) { s0[wv] = sw; s1[wv] = si; s2[wv] = sc; }
    __syncthreads();
    if (idx == 0) {
        float tw = 0.f, ti = 0.f, tc = 0.f;
#pragma unroll
        for (int i = 0; i < 16; ++i) { tw += s0[i]; ti += s1[i]; tc += s2[i]; }
        tw += 0.0001f;
        out[0] = ti / tw;
        out[1] = tc / tw;
    }
}

extern "C" void kernel_launch(void* const* d_in, const int* in_sizes, int n_in,
                              void* d_out, int out_size, void* d_ws, size_t ws_size,
                              hipStream_t stream) {
    const float* cls_logits  = (const float*)d_in[0];
    const float* iou_scores  = (const float*)d_in[1];
    const int*   target_ids  = (const int*)d_in[2];
    const int*   map_indices = (const int*)d_in[3];
    const float* map_ious    = (const float*)d_in[4];
    const float* pmp         = (const float*)d_in[5];
    const float* rand_vals   = (const float*)d_in[6];
    float* max_prob = (float*)d_ws;   // BS*CH floats = 4 KB
    float* out = (float*)d_out;

    max_prob_kernel<<<BS * CH, 256, 0, stream>>>(pmp, max_prob);
    loss_kernel<<<1, 1024, 0, stream>>>(cls_logits, iou_scores, target_ids,
                                        map_indices, map_ious, rand_vals,
                                        max_prob, out);
}

// Round 2
// 381.537 us; speedup vs baseline: 1.1158x; 1.1158x over previous
//
#include <hip/hip_runtime.h>
#include <math.h>

// Problem constants (fixed by setup_inputs): bs=16, ch=64, C=81, H=W=256
#define BS 16
#define CH 64
#define NC 81
#define HW 65536          // 256*256
#define FG 1              // FG_STCH
#define NJ (CH - FG)      // 63 items per batch

// ws layout (floats):
//   [0 .. 47]    partial sums: 16 blocks x {wsum, iou_part, ce_part}
//   [64 .. 1087] max_prob (BS*CH floats)
// All entries are written unconditionally every call (no reliance on ws state).

// Kernel 1: max over H*W for each (b, c). One block per channel.
// 256 threads x 64 float4 loads each; unroll 8 keeps <=32 load-VGPRs in flight.
__global__ __launch_bounds__(256) void max_prob_kernel(
    const float* __restrict__ pmp, float* __restrict__ max_prob) {
    const int bc = blockIdx.x;  // 0..1023
    const float4* p = (const float4*)(pmp + (size_t)bc * HW);
    const int t = threadIdx.x;
    float m = -INFINITY;
#pragma unroll 8
    for (int i = 0; i < 64; ++i) {
        float4 v = p[t + i * 256];
        m = fmaxf(m, fmaxf(fmaxf(v.x, v.y), fmaxf(v.z, v.w)));
    }
#pragma unroll
    for (int off = 32; off > 0; off >>= 1)
        m = fmaxf(m, __shfl_xor(m, off, 64));
    __shared__ float smax[4];
    if ((t & 63) == 0) smax[t >> 6] = m;
    __syncthreads();
    if (t == 0)
        max_prob[bc] = fmaxf(fmaxf(smax[0], smax[1]), fmaxf(smax[2], smax[3]));
}

// Kernel 2: per-batch partial loss. 16 blocks (one per batch), 256 threads:
// 4 threads per item split the 81-wide softmax loops; shfl-combine within
// the 4-lane group; block-reduce the 3 weighted sums; write partials.
__global__ __launch_bounds__(256) void loss_partial_kernel(
    const float* __restrict__ cls_logits,   // (BS, CH, NC)
    const float* __restrict__ iou_scores,   // (BS, CH, 1)
    const int*   __restrict__ target_ids,   // (BS, CH)
    const int*   __restrict__ map_indices,  // (BS, 2, CH)
    const float* __restrict__ map_ious,     // (BS, CH)
    const float* __restrict__ rand_vals,    // (BS, CH)
    const float* __restrict__ max_prob,     // (BS, CH) in ws
    float* __restrict__ partials)           // (BS, 3) in ws
{
    const int b = blockIdx.x;       // 0..15
    const int t = threadIdx.x;      // 0..255
    const int item = t >> 2;        // 0..63
    const int sub = t & 3;          // column-split lane within item
    float sw = 0.f, si = 0.f, sc = 0.f;
    if (item < NJ) {
        const int j  = item + FG;   // FG..CH-1
        const int pj = map_indices[b * 2 * CH + j];
        const int gj = map_indices[b * 2 * CH + CH + j];
        int cls = target_ids[b * CH + gj] - FG + 1;
        cls = cls > 0 ? cls : 0;
        const float iou = map_ious[b * CH + j];
        const float* lg = cls_logits + (size_t)(b * CH + pj) * NC;
        // partial max + stash values (<=21 per sub-thread)
        float vals[21];
        int n = 0;
        float mx = -INFINITY;
#pragma unroll
        for (int c = sub; c < NC; c += 4) {
            float v = lg[c];
            vals[n++] = v;
            mx = fmaxf(mx, v);
        }
        mx = fmaxf(mx, __shfl_xor(mx, 1, 64));
        mx = fmaxf(mx, __shfl_xor(mx, 2, 64));
        float s = 0.f;
        for (int k = 0; k < n; ++k) s += __expf(vals[k] - mx);
        s += __shfl_xor(s, 1, 64);
        s += __shfl_xor(s, 2, 64);
        if (sub == 0) {
            const float mp  = max_prob[b * CH + pj];
            const float rnd = rand_vals[b * CH + j];
            const bool remove = (mp < 0.1f) && (rnd < 0.9f);
            // w[] all ones: wght = remove ? 0 : (iou<0.2 ? 1 : 2)
            const float wght = remove ? 0.f : (iou < 0.2f ? 1.f : 2.f);
            const float y  = fabsf(iou_scores[b * CH + pj] - iou);
            const float il = (y < 0.1f) ? 5.f * y * y : (y - 0.05f);
            const float logp = lg[cls] - mx - __logf(s);
            sw = wght;
            si = il * wght;
            sc = -logp * wght;      // w[cls] == 1
        }
    }
    // block reduce (4 waves of 64)
#pragma unroll
    for (int off = 32; off > 0; off >>= 1) {
        sw += __shfl_xor(sw, off, 64);
        si += __shfl_xor(si, off, 64);
        sc += __shfl_xor(sc, off, 64);
    }
    __shared__ float s0[4], s1[4], s2[4];
    const int wv = t >> 6;
    if ((t & 63) == 0) { s0[wv] = sw; s1[wv] = si; s2[wv] = sc; }
    __syncthreads();
    if (t == 0) {
        partials[b * 3 + 0] = s0[0] + s0[1] + s0[2] + s0[3];
        partials[b * 3 + 1] = s1[0] + s1[1] + s1[2] + s1[3];
        partials[b * 3 + 2] = s2[0] + s2[1] + s2[2] + s2[3];
    }
}

// Kernel 3: combine 16 partial triples -> two scalars.
__global__ void final_kernel(const float* __restrict__ partials,
                             float* __restrict__ out) {
    float tw = 0.f, ti = 0.f, tc = 0.f;
#pragma unroll
    for (int i = 0; i < BS; ++i) {
        tw += partials[i * 3 + 0];
        ti += partials[i * 3 + 1];
        tc += partials[i * 3 + 2];
    }
    tw += 0.0001f;
    out[0] = ti / tw;
    out[1] = tc / tw;
}

extern "C" void kernel_launch(void* const* d_in, const int* in_sizes, int n_in,
                              void* d_out, int out_size, void* d_ws, size_t ws_size,
                              hipStream_t stream) {
    const float* cls_logits  = (const float*)d_in[0];
    const float* iou_scores  = (const float*)d_in[1];
    const int*   target_ids  = (const int*)d_in[2];
    const int*   map_indices = (const int*)d_in[3];
    const float* map_ious    = (const float*)d_in[4];
    const float* pmp         = (const float*)d_in[5];
    const float* rand_vals   = (const float*)d_in[6];
    float* wsf      = (float*)d_ws;
    float* partials = wsf;          // 48 floats
    float* max_prob = wsf + 64;     // 1024 floats
    float* out = (float*)d_out;

    max_prob_kernel<<<BS * CH, 256, 0, stream>>>(pmp, max_prob);
    loss_partial_kernel<<<BS, 256, 0, stream>>>(cls_logits, iou_scores,
                                                target_ids, map_indices,
                                                map_ious, rand_vals,
                                                max_prob, partials);
    final_kernel<<<1, 1, 0, stream>>>(partials, out);
}

// Round 3
// 316.197 us; speedup vs baseline: 1.3464x; 1.2066x over previous
//
#include <hip/hip_runtime.h>
#include <math.h>

// Problem constants (fixed by setup_inputs): bs=16, ch=64, C=81, H=W=256
#define BS 16
#define CH 64
#define NC 81
#define HW 65536          // 256*256
#define FG 1              // FG_STCH
#define NJ (CH - FG)      // 63 items per batch

// ws layout (floats):
//   [0 .. 47]    partial sums: 16 blocks x {wsum, iou_part, ce_part}
//   [64 .. 1087] entity flag per (b,c): 1.0 if max>=0.1 else 0.0
// All used entries are written unconditionally every call.

// Kernel 1: per-channel predicate "any element >= 0.1" with early exit.
// The reference only uses max_prob via (mp < 0.1), so the exact max is not
// needed — just the predicate. One 64-lane wave per channel; each iteration
// scans 256 floats (float4/lane); wave-uniform __any() exit. Worst case
// (all elements < 0.1) degenerates to the full scan — still correct.
__global__ __launch_bounds__(64) void entity_flag_kernel(
    const float* __restrict__ pmp, float* __restrict__ flag) {
    const int bc = blockIdx.x;  // 0..1023
    const float4* p = (const float4*)(pmp + (size_t)bc * HW);
    const int t = threadIdx.x;  // 0..63
    for (int i = 0; i < 256; ++i) {
        float4 v = p[t + i * 64];
        float m = fmaxf(fmaxf(v.x, v.y), fmaxf(v.z, v.w));
        if (__any(m >= 0.1f)) {          // wave-uniform
            if (t == 0) flag[bc] = 1.0f; // not removed
            return;
        }
    }
    if (t == 0) flag[bc] = 0.0f;         // all < 0.1 -> removable
}

// Kernel 2: per-batch partial loss. 16 blocks (one per batch), 256 threads:
// 4 threads per item split the 81-wide softmax loops; shfl-combine within
// the 4-lane group; block-reduce the 3 weighted sums; write partials.
__global__ __launch_bounds__(256) void loss_partial_kernel(
    const float* __restrict__ cls_logits,   // (BS, CH, NC)
    const float* __restrict__ iou_scores,   // (BS, CH, 1)
    const int*   __restrict__ target_ids,   // (BS, CH)
    const int*   __restrict__ map_indices,  // (BS, 2, CH)
    const float* __restrict__ map_ious,     // (BS, CH)
    const float* __restrict__ rand_vals,    // (BS, CH)
    const float* __restrict__ flag,         // (BS, CH) in ws
    float* __restrict__ partials)           // (BS, 3) in ws
{
    const int b = blockIdx.x;       // 0..15
    const int t = threadIdx.x;      // 0..255
    const int item = t >> 2;        // 0..63
    const int sub = t & 3;          // column-split lane within item
    float sw = 0.f, si = 0.f, sc = 0.f;
    if (item < NJ) {
        const int j  = item + FG;   // FG..CH-1
        const int pj = map_indices[b * 2 * CH + j];
        const int gj = map_indices[b * 2 * CH + CH + j];
        int cls = target_ids[b * CH + gj] - FG + 1;
        cls = cls > 0 ? cls : 0;
        const float iou = map_ious[b * CH + j];
        const float* lg = cls_logits + (size_t)(b * CH + pj) * NC;
        // partial max + stash values (<=21 per sub-thread)
        float vals[21];
        int n = 0;
        float mx = -INFINITY;
#pragma unroll
        for (int c = sub; c < NC; c += 4) {
            float v = lg[c];
            vals[n++] = v;
            mx = fmaxf(mx, v);
        }
        mx = fmaxf(mx, __shfl_xor(mx, 1, 64));
        mx = fmaxf(mx, __shfl_xor(mx, 2, 64));
        float s = 0.f;
        for (int k = 0; k < n; ++k) s += __expf(vals[k] - mx);
        s += __shfl_xor(s, 1, 64);
        s += __shfl_xor(s, 2, 64);
        if (sub == 0) {
            const float mp  = flag[b * CH + pj];   // 1.0 or 0.0
            const float rnd = rand_vals[b * CH + j];
            const bool remove = (mp < 0.1f) && (rnd < 0.9f);
            // w[] all ones: wght = remove ? 0 : (iou<0.2 ? 1 : 2)
            const float wght = remove ? 0.f : (iou < 0.2f ? 1.f : 2.f);
            const float y  = fabsf(iou_scores[b * CH + pj] - iou);
            const float il = (y < 0.1f) ? 5.f * y * y : (y - 0.05f);
            const float logp = lg[cls] - mx - __logf(s);
            sw = wght;
            si = il * wght;
            sc = -logp * wght;      // w[cls] == 1
        }
    }
    // block reduce (4 waves of 64)
#pragma unroll
    for (int off = 32; off > 0; off >>= 1) {
        sw += __shfl_xor(sw, off, 64);
        si += __shfl_xor(si, off, 64);
        sc += __shfl_xor(sc, off, 64);
    }
    __shared__ float s0[4], s1[4], s2[4];
    const int wv = t >> 6;
    if ((t & 63) == 0) { s0[wv] = sw; s1[wv] = si; s2[wv] = sc; }
    __syncthreads();
    if (t == 0) {
        partials[b * 3 + 0] = s0[0] + s0[1] + s0[2] + s0[3];
        partials[b * 3 + 1] = s1[0] + s1[1] + s1[2] + s1[3];
        partials[b * 3 + 2] = s2[0] + s2[1] + s2[2] + s2[3];
    }
}

// Kernel 3: combine 16 partial triples -> two scalars.
__global__ void final_kernel(const float* __restrict__ partials,
                             float* __restrict__ out) {
    float tw = 0.f, ti = 0.f, tc = 0.f;
#pragma unroll
    for (int i = 0; i < BS; ++i) {
        tw += partials[i * 3 + 0];
        ti += partials[i * 3 + 1];
        tc += partials[i * 3 + 2];
    }
    tw += 0.0001f;
    out[0] = ti / tw;
    out[1] = tc / tw;
}

extern "C" void kernel_launch(void* const* d_in, const int* in_sizes, int n_in,
                              void* d_out, int out_size, void* d_ws, size_t ws_size,
                              hipStream_t stream) {
    const float* cls_logits  = (const float*)d_in[0];
    const float* iou_scores  = (const float*)d_in[1];
    const int*   target_ids  = (const int*)d_in[2];
    const int*   map_indices = (const int*)d_in[3];
    const float* map_ious    = (const float*)d_in[4];
    const float* pmp         = (const float*)d_in[5];
    const float* rand_vals   = (const float*)d_in[6];
    float* wsf      = (float*)d_ws;
    float* partials = wsf;          // 48 floats
    float* flag     = wsf + 64;     // 1024 floats
    float* out = (float*)d_out;

    entity_flag_kernel<<<BS * CH, 64, 0, stream>>>(pmp, flag);
    loss_partial_kernel<<<BS, 256, 0, stream>>>(cls_logits, iou_scores,
                                                target_ids, map_indices,
                                                map_ious, rand_vals,
                                                flag, partials);
    final_kernel<<<1, 1, 0, stream>>>(partials, out);
}